// Round 4
// baseline (176.718 us; speedup 1.0000x reference)
//
#include <hip/hip_runtime.h>

// Problem constants (from reference)
#define NNZ_TOT   2097152
#define N_CELLS   4096
#define NUM_HID   128
#define CHUNK     128                   // nnz per wave
#define N_WAVES   (NNZ_TOT / CHUNK)     // 16384 waves

// ---------------------------------------------------------------------------
// Kernel 1: fuse first indirection: g_arr[i] = gidx[xc[i]] (gidx is 80 KB,
// cache-resident; coalesced in/out).
// ---------------------------------------------------------------------------
__global__ __launch_bounds__(256) void fuse_gidx_kernel(
    const int* __restrict__ xc, const int* __restrict__ gidx,
    int* __restrict__ g_arr)
{
    const int i = blockIdx.x * blockDim.x + threadIdx.x;
    if (i < NNZ_TOT) g_arr[i] = gidx[xc[i]];
}

// ---------------------------------------------------------------------------
// Kernel 2: one wave per 128-nnz chunk. Lane owns dims [lane*2, lane*2+2)
// (float2) -> each embs row read is one coalesced 512 B instruction.
// Fast path (chunk entirely in one row, ~75% of chunks): branchless
// 16-deep gather groups -> max loads in flight. Slow path: 8-groups with
// row-change flushes. Rows sorted -> register accumulate + atomic flush.
// __launch_bounds__(256, 8): allow up to 64 VGPRs at full occupancy so the
// compiler can keep 16 float2 gather results live (R3's 20-VGPR allocation
// serialized the gathers).
// ---------------------------------------------------------------------------
__device__ __forceinline__ void flush_row(float* __restrict__ out, int row,
                                          int h, float2 acc) {
    float* o = &out[(long)row * NUM_HID + h];
    atomicAdd(o + 0, acc.x);
    atomicAdd(o + 1, acc.y);
}

__global__ __launch_bounds__(256, 8) void omics_chunk_kernel(
    const float* __restrict__ xv,    // [NNZ] values
    const int*   __restrict__ xr,    // [NNZ] rows (sorted)
    const int*   __restrict__ g_arr, // [NNZ] fused gene ids
    const float* __restrict__ embs,  // [N_PRETRAINED, 128]
    float*       __restrict__ out)   // [N_CELLS, 128]
{
    const int wave = (blockIdx.x * blockDim.x + threadIdx.x) >> 6;
    const int lane = threadIdx.x & 63;
    const int base = __builtin_amdgcn_readfirstlane(wave * CHUNK);
    const int h    = lane * 2;

    const int rFirst = xr[base];
    const int rLast  = xr[base + CHUNK - 1];

    if (rFirst == rLast) {
        // ---- fast path: whole chunk in one row, zero branches inside ----
        float2 acc = make_float2(0.f, 0.f);
        for (int it = 0; it < CHUNK; it += 16) {
            int   g[16];
            float v[16];
            #pragma unroll
            for (int j = 0; j < 16; ++j) {
                g[j] = g_arr[base + it + j];   // uniform -> s_load
                v[j] = xv[base + it + j];      // uniform -> s_load
            }
            float2 f[16];
            #pragma unroll
            for (int j = 0; j < 16; ++j)
                f[j] = *reinterpret_cast<const float2*>(
                    &embs[(long)g[j] * NUM_HID + h]);
            #pragma unroll
            for (int j = 0; j < 16; ++j) {
                acc.x = fmaf(v[j], f[j].x, acc.x);
                acc.y = fmaf(v[j], f[j].y, acc.y);
            }
        }
        flush_row(out, rFirst, h, acc);
    } else {
        // ---- slow path: chunk crosses >=1 row boundary ----
        float2 acc = make_float2(0.f, 0.f);
        int cur = rFirst;
        for (int it = 0; it < CHUNK; it += 8) {
            const int i0 = base + it;
            const int rA = xr[i0];
            const int rB = xr[i0 + 7];
            if (rA == rB) {
                if (rA != cur) { flush_row(out, cur, h, acc);
                                 cur = rA; acc = make_float2(0.f, 0.f); }
                int   g[8];
                float v[8];
                #pragma unroll
                for (int j = 0; j < 8; ++j) {
                    g[j] = g_arr[i0 + j];
                    v[j] = xv[i0 + j];
                }
                float2 f[8];
                #pragma unroll
                for (int j = 0; j < 8; ++j)
                    f[j] = *reinterpret_cast<const float2*>(
                        &embs[(long)g[j] * NUM_HID + h]);
                #pragma unroll
                for (int j = 0; j < 8; ++j) {
                    acc.x = fmaf(v[j], f[j].x, acc.x);
                    acc.y = fmaf(v[j], f[j].y, acc.y);
                }
            } else {
                #pragma unroll
                for (int j = 0; j < 8; ++j) {
                    const int r = xr[i0 + j];
                    if (r != cur) { flush_row(out, cur, h, acc);
                                    cur = r; acc = make_float2(0.f, 0.f); }
                    const int   gg = g_arr[i0 + j];
                    const float vv = xv[i0 + j];
                    const float2 ff = *reinterpret_cast<const float2*>(
                        &embs[(long)gg * NUM_HID + h]);
                    acc.x = fmaf(vv, ff.x, acc.x);
                    acc.y = fmaf(vv, ff.y, acc.y);
                }
            }
        }
        flush_row(out, cur, h, acc);
    }
}

extern "C" void kernel_launch(void* const* d_in, const int* in_sizes, int n_in,
                              void* d_out, int out_size, void* d_ws, size_t ws_size,
                              hipStream_t stream) {
    const float* xv   = (const float*)d_in[0];
    const int*   xr   = (const int*)  d_in[1];
    const int*   xc   = (const int*)  d_in[2];
    const int*   gidx = (const int*)  d_in[3];
    const float* embs = (const float*)d_in[4];
    float*       out  = (float*)d_out;

    // Atomically accumulated -> zero first (harness poisons with 0xAA).
    hipMemsetAsync(out, 0, (size_t)out_size * sizeof(float), stream);

    int* g_arr = (int*)d_ws;   // 8 MB; ws guaranteed >= out scratch needs
    fuse_gidx_kernel<<<(NNZ_TOT + 255) / 256, 256, 0, stream>>>(xc, gidx, g_arr);

    const int blocks = (N_WAVES * 64) / 256;   // 4096 blocks x 256 threads
    omics_chunk_kernel<<<blocks, 256, 0, stream>>>(xv, xr, g_arr, embs, out);
}